// Round 1
// baseline (126.392 us; speedup 1.0000x reference)
//
#include <hip/hip_runtime.h>

// MS_SSA_Conv: spiking self-attention, T=4, C=512, N=196 (14x14), fp32.
// Key insight: all matmul inputs are spikes {0,1} with ~3-4% density ->
// sparse masked column-sums of W instead of dense GEMM. All tensors kept in
// [T,C,N] layout (to_heads is a pure relabeling: c = nh*64 + hd).
//
// K0: transpose 4 weight matrices W[o][c] -> Wt[c][o] (coalesced o-reads),
//     zero kvsum accumulator (ws is re-poisoned 0xAA before every launch).
// KA: one block per n: LIF(x) -> xs spikes, compact active c per t,
//     sparse-accumulate yq/yk/yv, BN+LIF -> sq/sk/sv, store sq bitmask,
//     atomicAdd(sk&sv) into kvsum[t][c].
// KB: one block per n: talking-heads LIF(kvsum) -> skv (recomputed per block,
//     8KB read, cheaper than a 3rd sync point), attn bits = sq & skv,
//     sparse-accumulate proj, fused bias+BN+identity epilogue.

#define TT 4
#define CC 512
#define NN 196
#define BEPS 1e-5f

// ws layout in floats
#define WQT_OFF 0
#define WKT_OFF (512 * 512)
#define WVT_OFF (2 * 512 * 512)
#define WPT_OFF (3 * 512 * 512)
#define KV_OFF  (4 * 512 * 512)            // T*C = 2048 floats
#define SQ_OFF  (4 * 512 * 512 + 2048)     // T*N*16 u32 words = 12544
// total: 1,063,168 floats = 4.06 MB of ws

__global__ __launch_bounds__(256) void k0_prep(
    const float* __restrict__ qw, const float* __restrict__ kw,
    const float* __restrict__ vw, const float* __restrict__ pw,
    float* __restrict__ ws)
{
    __shared__ float tile[64][65];  // +1 pad: conflict-free transpose
    const int b   = blockIdx.x;     // 256 blocks: 4 matrices x 8x8 tiles of 64x64
    const int mat = b >> 6;
    const int t6  = b & 63;
    const int to  = (t6 >> 3) * 64; // o-tile origin
    const int tc  = (t6 & 7) * 64;  // c-tile origin
    const float* W = (mat == 0) ? qw : (mat == 1) ? kw : (mat == 2) ? vw : pw;
    float* Wt = ws + (size_t)mat * (512 * 512);
    const int lr = threadIdx.x >> 6;   // 0..3
    const int lc = threadIdx.x & 63;
#pragma unroll
    for (int i = 0; i < 16; ++i) {
        int r = i * 4 + lr;
        tile[r][lc] = W[(size_t)(to + r) * 512 + (tc + lc)];   // coalesced read
    }
    __syncthreads();
#pragma unroll
    for (int i = 0; i < 16; ++i) {
        int r = i * 4 + lr;   // c-local
        Wt[(size_t)(tc + r) * 512 + (to + lc)] = tile[lc][r];  // coalesced write
    }
    if (b == 0) {
        for (int i = threadIdx.x; i < TT * CC; i += 256) ws[KV_OFF + i] = 0.0f;
    }
}

__device__ __forceinline__ int bn_lif4(const float* acc, float sc, float of, float vth) {
    float v = 0.0f;
    int bits = 0;
#pragma unroll
    for (int t = 0; t < TT; ++t) {
        float y = acc[t] * sc + of;
        v = v + (y - v) * 0.5f;            // v += (y - v)/tau, tau=2
        if (v >= vth) { bits |= (1 << t); v = 0.0f; }
    }
    return bits;
}

// ballot-compact: append set lanes' channel ids to act[t][]
__device__ __forceinline__ void compact_append(int flag, int ch, int lane,
                                               unsigned short* actrow, int* cntp)
{
    unsigned long long m = __ballot(flag);
    int base = 0;
    if (lane == 0 && m) base = atomicAdd(cntp, __popcll(m));
    base = __shfl(base, 0);
    if (flag) actrow[base + __popcll(m & ((1ull << lane) - 1ull))] = (unsigned short)ch;
}

__global__ __launch_bounds__(256) void ka_qkv(
    const float* __restrict__ x, float* __restrict__ ws,
    const float* __restrict__ qg, const float* __restrict__ qb,
    const float* __restrict__ qm, const float* __restrict__ qv,
    const float* __restrict__ kg, const float* __restrict__ kb,
    const float* __restrict__ km, const float* __restrict__ kvv,
    const float* __restrict__ vg, const float* __restrict__ vb,
    const float* __restrict__ vm, const float* __restrict__ vvv)
{
    const int n    = blockIdx.x;      // 0..195
    const int tid  = threadIdx.x;     // owns channels tid and tid+256
    const int lane = tid & 63;
    const int wave = tid >> 6;
    __shared__ unsigned short act[TT][CC];
    __shared__ int cnt[TT];
    if (tid < TT) cnt[tid] = 0;
    __syncthreads();

    // --- shortcut LIF on x (recomputed locally; depends only on this n) ---
    int xf0 = 0, xf1 = 0;
    {
        float v0 = 0.0f, v1 = 0.0f;
#pragma unroll
        for (int t = 0; t < TT; ++t) {
            float a0 = x[(size_t)(t * CC + tid) * NN + n];
            float a1 = x[(size_t)(t * CC + tid + 256) * NN + n];
            v0 = v0 + (a0 - v0) * 0.5f;
            v1 = v1 + (a1 - v1) * 0.5f;
            if (v0 >= 1.0f) { xf0 |= (1 << t); v0 = 0.0f; }
            if (v1 >= 1.0f) { xf1 |= (1 << t); v1 = 0.0f; }
        }
    }
#pragma unroll
    for (int t = 0; t < TT; ++t) {
        compact_append((xf0 >> t) & 1, tid,       lane, act[t], &cnt[t]);
        compact_append((xf1 >> t) & 1, tid + 256, lane, act[t], &cnt[t]);
    }
    __syncthreads();

    // --- sparse accumulate: y[o] = sum over active c of Wt[c][o] ---
    float aq0[TT] = {0,0,0,0}, aq1[TT] = {0,0,0,0};
    float ak0[TT] = {0,0,0,0}, ak1[TT] = {0,0,0,0};
    float av0[TT] = {0,0,0,0}, av1[TT] = {0,0,0,0};
    const float* Wqt = ws + WQT_OFF;
    const float* Wkt = ws + WKT_OFF;
    const float* Wvt = ws + WVT_OFF;
#pragma unroll
    for (int t = 0; t < TT; ++t) {
        const int ct = cnt[t];
        for (int i = 0; i < ct; ++i) {
            const int c = act[t][i];
            const float* rq = Wqt + (size_t)c * CC;
            const float* rk = Wkt + (size_t)c * CC;
            const float* rv = Wvt + (size_t)c * CC;
            aq0[t] += rq[tid]; aq1[t] += rq[tid + 256];
            ak0[t] += rk[tid]; ak1[t] += rk[tid + 256];
            av0[t] += rv[tid]; av1[t] += rv[tid + 256];
        }
    }

    // --- BN + LIF (v_th = 1) per output channel ---
    int sqb0, sqb1, skb0, skb1, svb0, svb1;
    {
        float sc = qg[tid] / sqrtf(qv[tid] + BEPS);
        sqb0 = bn_lif4(aq0, sc, qb[tid] - qm[tid] * sc, 1.0f);
        sc = qg[tid + 256] / sqrtf(qv[tid + 256] + BEPS);
        sqb1 = bn_lif4(aq1, sc, qb[tid + 256] - qm[tid + 256] * sc, 1.0f);
        sc = kg[tid] / sqrtf(kvv[tid] + BEPS);
        skb0 = bn_lif4(ak0, sc, kb[tid] - km[tid] * sc, 1.0f);
        sc = kg[tid + 256] / sqrtf(kvv[tid + 256] + BEPS);
        skb1 = bn_lif4(ak1, sc, kb[tid + 256] - km[tid + 256] * sc, 1.0f);
        sc = vg[tid] / sqrtf(vvv[tid] + BEPS);
        svb0 = bn_lif4(av0, sc, vb[tid] - vm[tid] * sc, 1.0f);
        sc = vg[tid + 256] / sqrtf(vvv[tid + 256] + BEPS);
        svb1 = bn_lif4(av1, sc, vb[tid + 256] - vm[tid + 256] * sc, 1.0f);
    }

    // --- store sq bitmask; accumulate kvsum[t][c] += sk & sv ---
    unsigned* sqg = (unsigned*)(ws + SQ_OFF);
    float* kvsum = ws + KV_OFF;
#pragma unroll
    for (int t = 0; t < TT; ++t) {
        unsigned long long m = __ballot((sqb0 >> t) & 1);
        if (lane == 0) {
            sqg[((size_t)t * NN + n) * 16 + wave * 2]     = (unsigned)(m & 0xffffffffULL);
            sqg[((size_t)t * NN + n) * 16 + wave * 2 + 1] = (unsigned)(m >> 32);
        }
        m = __ballot((sqb1 >> t) & 1);
        if (lane == 0) {
            sqg[((size_t)t * NN + n) * 16 + 8 + wave * 2]     = (unsigned)(m & 0xffffffffULL);
            sqg[((size_t)t * NN + n) * 16 + 8 + wave * 2 + 1] = (unsigned)(m >> 32);
        }
        if (((skb0 >> t) & 1) && ((svb0 >> t) & 1)) atomicAdd(&kvsum[t * CC + tid], 1.0f);
        if (((skb1 >> t) & 1) && ((svb1 >> t) & 1)) atomicAdd(&kvsum[t * CC + tid + 256], 1.0f);
    }
}

__global__ __launch_bounds__(256) void kb_proj(
    const float* __restrict__ x, const float* __restrict__ ws,
    const float* __restrict__ pbias,
    const float* __restrict__ pg, const float* __restrict__ pb,
    const float* __restrict__ pm, const float* __restrict__ pv,
    float* __restrict__ out)
{
    const int n    = blockIdx.x;
    const int tid  = threadIdx.x;
    const int lane = tid & 63;
    __shared__ unsigned short act[TT][CC];
    __shared__ int cnt[TT];
    if (tid < TT) cnt[tid] = 0;
    __syncthreads();

    const float* kvsum = ws + KV_OFF;
    const unsigned* sqg = (const unsigned*)(ws + SQ_OFF);

    // talking-heads LIF (v_th = 0.5) on kvsum; AND with sq bit for this n
    int f0 = 0, f1 = 0;
    {
        float v0 = 0.0f, v1 = 0.0f;
#pragma unroll
        for (int t = 0; t < TT; ++t) {
            float a0 = kvsum[t * CC + tid];
            float a1 = kvsum[t * CC + tid + 256];
            v0 = v0 + (a0 - v0) * 0.5f;
            v1 = v1 + (a1 - v1) * 0.5f;
            const int s0 = (v0 >= 0.5f), s1 = (v1 >= 0.5f);
            if (s0) v0 = 0.0f;
            if (s1) v1 = 0.0f;
            const unsigned w0 = sqg[((size_t)t * NN + n) * 16 + (tid >> 5)];
            const unsigned w1 = sqg[((size_t)t * NN + n) * 16 + 8 + (tid >> 5)];
            if (s0 && ((w0 >> (tid & 31)) & 1)) f0 |= (1 << t);
            if (s1 && ((w1 >> (tid & 31)) & 1)) f1 |= (1 << t);
        }
    }
#pragma unroll
    for (int t = 0; t < TT; ++t) {
        compact_append((f0 >> t) & 1, tid,       lane, act[t], &cnt[t]);
        compact_append((f1 >> t) & 1, tid + 256, lane, act[t], &cnt[t]);
    }
    __syncthreads();

    float a0[TT] = {0,0,0,0}, a1[TT] = {0,0,0,0};
    const float* Wpt = ws + WPT_OFF;
#pragma unroll
    for (int t = 0; t < TT; ++t) {
        const int ct = cnt[t];
        for (int i = 0; i < ct; ++i) {
            const int c = act[t][i];
            const float* r = Wpt + (size_t)c * CC;
            a0[t] += r[tid];
            a1[t] += r[tid + 256];
        }
    }

    // epilogue: (acc + bias)*scale + offset + identity
    {
        const float sc0 = pg[tid] / sqrtf(pv[tid] + BEPS);
        const float of0 = pb[tid] - pm[tid] * sc0;
        const float bi0 = pbias[tid];
        const float sc1 = pg[tid + 256] / sqrtf(pv[tid + 256] + BEPS);
        const float of1 = pb[tid + 256] - pm[tid + 256] * sc1;
        const float bi1 = pbias[tid + 256];
#pragma unroll
        for (int t = 0; t < TT; ++t) {
            const size_t i0 = (size_t)(t * CC + tid) * NN + n;
            const size_t i1 = (size_t)(t * CC + tid + 256) * NN + n;
            out[i0] = (a0[t] + bi0) * sc0 + of0 + x[i0];
            out[i1] = (a1[t] + bi1) * sc1 + of1 + x[i1];
        }
    }
}

extern "C" void kernel_launch(void* const* d_in, const int* in_sizes, int n_in,
                              void* d_out, int out_size, void* d_ws, size_t ws_size,
                              hipStream_t stream) {
    const float* x     = (const float*)d_in[0];
    const float* qw    = (const float*)d_in[1];
    const float* kw    = (const float*)d_in[2];
    const float* vw    = (const float*)d_in[3];
    const float* pw    = (const float*)d_in[4];
    const float* pbias = (const float*)d_in[5];
    const float* qg = (const float*)d_in[6],  *qb = (const float*)d_in[7];
    const float* qm = (const float*)d_in[8],  *qv = (const float*)d_in[9];
    const float* kg = (const float*)d_in[10], *kb = (const float*)d_in[11];
    const float* km = (const float*)d_in[12], *kv = (const float*)d_in[13];
    const float* vg = (const float*)d_in[14], *vb = (const float*)d_in[15];
    const float* vm = (const float*)d_in[16], *vv = (const float*)d_in[17];
    const float* pg = (const float*)d_in[18], *pb = (const float*)d_in[19];
    const float* pm = (const float*)d_in[20], *pv = (const float*)d_in[21];
    float* ws  = (float*)d_ws;
    float* out = (float*)d_out;

    hipLaunchKernelGGL(k0_prep, dim3(256), dim3(256), 0, stream, qw, kw, vw, pw, ws);
    hipLaunchKernelGGL(ka_qkv, dim3(196), dim3(256), 0, stream, x, ws,
                       qg, qb, qm, qv, kg, kb, km, kv, vg, vb, vm, vv);
    hipLaunchKernelGGL(kb_proj, dim3(196), dim3(256), 0, stream, x, ws,
                       pbias, pg, pb, pm, pv, out);
}